// Round 13
// baseline (27.016 us; speedup 1.0000x reference)
//
#include <hip/hip_runtime.h>
#include <hip/hip_bf16.h>

// TrajectoryInformedSplatAttention — float4 + DPP reduce + NT stores
//   + FORCED register-resident window (anti-rematerialization pin).
// B=4, S=4096, D=1024, maxd=8.
//
// traj[b,s,:] = sum_{jr=0..8} g[s][jr] * emb[b, s-8+jr, :]   (telescoped)
//   g[jr] = (c[jr-1]-c[jr])/wsum, c[j] = lin(s,j)*q[i], i=s-8+j
//   q = tanh(2*mag)/mag (0 if mag<=1e-6), wsum = max(sum lin*tanh(2*mag),1e-8)
//
// Key discovery (R12 post-mortem): VGPR_Count=36 in R1 proves the compiler
// REMATERIALIZES the "register window" — it reloads all 40 rows from memory
// in Phase C2 rather than keeping them live across __syncthreads. The empty
// asm pin below makes each win[] component opaquely-modified, so a reload
// would be illegal -> true register residency, second pass reads VGPRs.

constexpr int B_ = 4;
constexpr int S_ = 4096;
constexpr int D_ = 1024;
constexpr int MAXD  = 8;
constexpr int CHUNK = 32;
constexpr int ROWS  = CHUNK + MAXD;      // 40-row register window
constexpr int NDIFF = ROWS - 1;          // 39 adjacent diffs
constexpr int NCH   = S_ / CHUNK;        // 128 s-chunks
constexpr int NWG   = B_ * NCH;          // 512 blocks
constexpr int NXCD  = 8;

typedef float fx4 __attribute__((ext_vector_type(4)));

// x += dpp_shifted(x); old=0 so shifted-in / unmasked rows contribute 0.
template <int CTRL, int ROW_MASK>
__device__ __forceinline__ float dpp_add(float x) {
    const int t = __builtin_amdgcn_update_dpp(0, __float_as_int(x),
                                              CTRL, ROW_MASK, 0xf, false);
    return x + __int_as_float(t);
}

// Full 64-lane sum -> lane 63. row_shr:N = 0x110|N, bcast15=0x142, bcast31=0x143.
__device__ __forceinline__ float wave_reduce_dpp(float x) {
    x = dpp_add<0x111, 0xf>(x);   // += lane-1
    x = dpp_add<0x112, 0xf>(x);   // += lane-2
    x = dpp_add<0x114, 0xf>(x);   // += lane-4
    x = dpp_add<0x118, 0xf>(x);   // += lane-8   -> lane 15+16k = row sums
    x = dpp_add<0x142, 0xa>(x);   // rows 1,3 += bcast(lane15/47)
    x = dpp_add<0x143, 0xc>(x);   // rows 2,3 += bcast(lane31)   -> lane63 total
    return x;
}

__global__ __launch_bounds__(256, 2)
void traj_splat_kernel(const float* __restrict__ emb, float* __restrict__ out) {
    // XCD swizzle (NWG % 8 == 0 -> bijective): consecutive lin on one XCD are
    // consecutive s-chunks -> 8-row halo is an L2 hit.
    const int bid = blockIdx.x;
    const int lin = (bid % NXCD) * (NWG / NXCD) + bid / NXCD;
    const int schunk = lin & (NCH - 1);
    const int b      = lin >> 7;

    const int s0   = schunk * CHUNK;
    const int lane = threadIdx.x & 63;
    const int wave = threadIdx.x >> 6;    // 4 waves
    const int d0   = threadIdx.x * 4;     // 256 threads * 4 floats = 1024 = D

    const float* __restrict__ embB = emb + (size_t)b * S_ * D_;

    __shared__ float part[NDIFF][5];      // 4 wave-sums/diff + 1 pad
    __shared__ float smagw[NDIFF];
    __shared__ float sq[NDIFF];
    __shared__ float gco[CHUNK][12];

    // ---- Phase A: 40-row window, float4/thread (1 KiB per load inst) ----
    float4 win[ROWS];
    #pragma unroll
    for (int r = 0; r < ROWS; ++r) {
        const int row = s0 - MAXD + r;    // max = s0+31 <= S-1
        win[r] = (row >= 0) ? *(const float4*)(embB + (size_t)row * D_ + d0)
                            : make_float4(0.f, 0.f, 0.f, 0.f);
    }

    // ---- Phase B: 39 full-D diff magnitudes via DPP (VALU-only reduce) ----
    #pragma unroll
    for (int li = 0; li < NDIFF; ++li) {
        const float4 a = win[li], c = win[li + 1];
        const float dx = c.x - a.x, dy = c.y - a.y;
        const float dz = c.z - a.z, dw = c.w - a.w;
        float sum = dx * dx + dy * dy + dz * dz + dw * dw;
        sum = wave_reduce_dpp(sum);
        if (lane == 63) part[li][wave] = sum;
    }

    // ---- Liveness pin: forbid rematerialization of the window across the
    // barrier. Empty asm "modifies" each component -> a reload from global
    // would yield a stale value -> compiler must keep them in VGPRs.
    #pragma unroll
    for (int r = 0; r < ROWS; ++r)
        asm volatile("" : "+v"(win[r].x), "+v"(win[r].y),
                          "+v"(win[r].z), "+v"(win[r].w));

    __syncthreads();

    if (threadIdx.x < NDIFF) {
        const int li = threadIdx.x;
        const float s2 = part[li][0] + part[li][1] + part[li][2] + part[li][3];
        const float mag = sqrtf(s2);                     // FULL-D magnitude
        const float mw  = tanhf(2.f * mag);
        smagw[li] = mw;
        sq[li]    = (mag > 1e-6f) ? (mw / mag) : 0.f;
    }
    __syncthreads();

    // ---- Phase C1: CHUNK threads build the 9 telescoped coefficients per s ----
    if (threadIdx.x < CHUNK) {
        const int sl = threadIdx.x;
        const int s  = s0 + sl;
        const int ws = min(MAXD, s);
        const int lo = MAXD - ws;
        const float rden = 0.9f / (float)max(ws - 1, 1);

        float cpad[MAXD + 2];
        #pragma unroll
        for (int t = 0; t < MAXD + 2; ++t) cpad[t] = 0.f;

        float wsum = 0.f;
        #pragma unroll
        for (int j = 0; j < MAXD; ++j) {
            if (j >= lo) {
                const int li = sl + j;               // diff at global index s-8+j
                const float lin2 = (ws > 1) ? (0.1f + rden * (float)(j - lo)) : 0.1f;
                wsum += lin2 * smagw[li];
                cpad[j + 1] = lin2 * sq[li];
            }
        }
        const float inv = 1.f / fmaxf(wsum, 1e-8f);
        #pragma unroll
        for (int jr = 0; jr <= MAXD; ++jr)
            gco[sl][jr] = (cpad[jr] - cpad[jr + 1]) * inv;
    }
    __syncthreads();

    // ---- Phase C2: outputs from (genuinely) register-resident window ----
    float* outB = out + ((size_t)b * S_ + s0) * D_ + d0;
    #pragma unroll
    for (int sl = 0; sl < CHUNK; ++sl) {
        const float4 g0 = *(const float4*)&gco[sl][0];   // g[0..3] (broadcast)
        const float4 g1 = *(const float4*)&gco[sl][4];   // g[4..7]
        const float  g8 = gco[sl][8];

        float ax = g0.x * win[sl].x;
        float ay = g0.x * win[sl].y;
        float az = g0.x * win[sl].z;
        float aw = g0.x * win[sl].w;
        const float gs[8] = {g0.y, g0.z, g0.w, g1.x, g1.y, g1.z, g1.w, g8};
        #pragma unroll
        for (int jr = 1; jr <= MAXD; ++jr) {
            const float g = gs[jr - 1];
            ax += g * win[sl + jr].x;
            ay += g * win[sl + jr].y;
            az += g * win[sl + jr].z;
            aw += g * win[sl + jr].w;
        }
        fx4 acc4; acc4.x = ax; acc4.y = ay; acc4.z = az; acc4.w = aw;
        __builtin_nontemporal_store(acc4, (fx4*)(outB + (size_t)sl * D_));
    }
}

extern "C" void kernel_launch(void* const* d_in, const int* in_sizes, int n_in,
                              void* d_out, int out_size, void* d_ws, size_t ws_size,
                              hipStream_t stream) {
    const float* emb = (const float*)d_in[0];
    float* out = (float*)d_out;

    dim3 grid(NWG);      // 512 blocks, swizzled in-kernel
    dim3 block(256);
    traj_splat_kernel<<<grid, block, 0, stream>>>(emb, out);
}

// Round 14
// 25.950 us; speedup vs baseline: 1.0410x; 1.0410x over previous
//
#include <hip/hip_runtime.h>
#include <hip/hip_bf16.h>

// TrajectoryInformedSplatAttention — single-barrier, wave-autonomous finalize.
// B=4, S=4096, D=1024, maxd=8.
//
// traj[b,s,:] = sum_{jr=0..8} g[s][jr] * emb[b, s-8+jr, :]   (telescoped)
//   g[jr] = (c[jr-1]-c[jr])/wsum, c[j] = lin(s,j)*q[i], i=s-8+j
//   q = tanh(2*mag)/mag (0 if mag<=1e-6), wsum = max(sum lin*tanh(2*mag),1e-8)
//
// vs R12 (best, 25.9us): only the 39x4 partial sums are cross-wave data, so
// keep ONE block barrier after writing them. Each wave then REDUNDANTLY
// finalizes all 39 mags (lanes 0..38 in parallel) and its own coefficient
// table into per-wave LDS slabs, ordered by wave-internal lgkmcnt fences
// (lockstep wave => no block barrier). Removes 2 of 3 __syncthreads and the
// 32-of-256-threads serial phase. Epilogue/loads identical to R12.
// (R13's register pin REMOVED — rematerialized cache reloads are free;
// pinning cost 1.1us.)

constexpr int B_ = 4;
constexpr int S_ = 4096;
constexpr int D_ = 1024;
constexpr int MAXD  = 8;
constexpr int CHUNK = 32;
constexpr int ROWS  = CHUNK + MAXD;      // 40-row window
constexpr int NDIFF = ROWS - 1;          // 39 adjacent diffs
constexpr int NCH   = S_ / CHUNK;        // 128 s-chunks
constexpr int NWG   = B_ * NCH;          // 512 blocks
constexpr int NXCD  = 8;
constexpr int NWAVE = 4;

typedef float fx4 __attribute__((ext_vector_type(4)));

// x += dpp_shifted(x); old=0 so shifted-in / unmasked rows contribute 0.
template <int CTRL, int ROW_MASK>
__device__ __forceinline__ float dpp_add(float x) {
    const int t = __builtin_amdgcn_update_dpp(0, __float_as_int(x),
                                              CTRL, ROW_MASK, 0xf, false);
    return x + __int_as_float(t);
}

// Full 64-lane sum -> lane 63. row_shr:N = 0x110|N, bcast15=0x142, bcast31=0x143.
__device__ __forceinline__ float wave_reduce_dpp(float x) {
    x = dpp_add<0x111, 0xf>(x);   // += lane-1
    x = dpp_add<0x112, 0xf>(x);   // += lane-2
    x = dpp_add<0x114, 0xf>(x);   // += lane-4
    x = dpp_add<0x118, 0xf>(x);   // += lane-8   -> lane 15+16k = row sums
    x = dpp_add<0x142, 0xa>(x);   // rows 1,3 += bcast(lane15/47)
    x = dpp_add<0x143, 0xc>(x);   // rows 2,3 += bcast(lane31)   -> lane63 total
    return x;
}

// Wave-internal LDS ordering: drain this wave's LDS ops; no block barrier.
__device__ __forceinline__ void wave_lds_fence() {
    asm volatile("s_waitcnt lgkmcnt(0)" ::: "memory");
    __builtin_amdgcn_sched_barrier(0);
}

__global__ __launch_bounds__(256, 2)
void traj_splat_kernel(const float* __restrict__ emb, float* __restrict__ out) {
    // XCD swizzle (NWG % 8 == 0 -> bijective): consecutive lin on one XCD are
    // consecutive s-chunks -> 8-row halo is an L2 hit.
    const int bid = blockIdx.x;
    const int lin = (bid % NXCD) * (NWG / NXCD) + bid / NXCD;
    const int schunk = lin & (NCH - 1);
    const int b      = lin >> 7;

    const int s0   = schunk * CHUNK;
    const int lane = threadIdx.x & 63;
    const int wave = threadIdx.x >> 6;    // 4 waves
    const int d0   = threadIdx.x * 4;     // 256 threads * 4 floats = 1024 = D

    const float* __restrict__ embB = emb + (size_t)b * S_ * D_;

    __shared__ float part[NDIFF][5];              // cross-wave: 4 partials + pad
    __shared__ float smagw[NWAVE][NDIFF + 1];     // per-wave slabs below
    __shared__ float sq[NWAVE][NDIFF + 1];
    __shared__ float gco[NWAVE][CHUNK][12];

    // ---- Phase A: 40-row window, float4/thread (1 KiB per load inst) ----
    float4 win[ROWS];
    #pragma unroll
    for (int r = 0; r < ROWS; ++r) {
        const int row = s0 - MAXD + r;    // max = s0+31 <= S-1
        win[r] = (row >= 0) ? *(const float4*)(embB + (size_t)row * D_ + d0)
                            : make_float4(0.f, 0.f, 0.f, 0.f);
    }

    // ---- Phase B: 39 full-D diff partials via DPP; lane63 -> LDS ----
    #pragma unroll
    for (int li = 0; li < NDIFF; ++li) {
        const float4 a = win[li], c = win[li + 1];
        const float dx = c.x - a.x, dy = c.y - a.y;
        const float dz = c.z - a.z, dw = c.w - a.w;
        float sum = dx * dx + dy * dy + dz * dz + dw * dw;
        sum = wave_reduce_dpp(sum);
        if (lane == 63) part[li][wave] = sum;
    }

    // ---- The ONLY block barrier: partials visible to all waves ----
    asm volatile("s_waitcnt lgkmcnt(0)" ::: "memory");
    __builtin_amdgcn_s_barrier();

    // ---- Per-wave redundant finalize: lanes 0..38 do all 39 mags ----
    if (lane < NDIFF) {
        const float s2 = part[lane][0] + part[lane][1]
                       + part[lane][2] + part[lane][3];
        const float mag = sqrtf(s2);                 // FULL-D magnitude
        const float mw  = tanhf(2.f * mag);
        smagw[wave][lane] = mw;
        sq[wave][lane]    = (mag > 1e-6f) ? (mw / mag) : 0.f;
    }
    wave_lds_fence();

    // ---- Per-wave coefficients: lanes 0..31, own slab only ----
    if (lane < CHUNK) {
        const int sl = lane;
        const int s  = s0 + sl;
        const int ws = min(MAXD, s);
        const int lo = MAXD - ws;
        const float rden = 0.9f / (float)max(ws - 1, 1);

        float cpad[MAXD + 2];
        #pragma unroll
        for (int t = 0; t < MAXD + 2; ++t) cpad[t] = 0.f;

        float wsum = 0.f;
        #pragma unroll
        for (int j = 0; j < MAXD; ++j) {
            if (j >= lo) {
                const int li = sl + j;               // block-diff = global s-8+j
                const float lin2 = (ws > 1) ? (0.1f + rden * (float)(j - lo)) : 0.1f;
                wsum += lin2 * smagw[wave][li];
                cpad[j + 1] = lin2 * sq[wave][li];
            }
        }
        const float inv = 1.f / fmaxf(wsum, 1e-8f);
        #pragma unroll
        for (int jr = 0; jr <= MAXD; ++jr)
            gco[wave][sl][jr] = (cpad[jr] - cpad[jr + 1]) * inv;
    }
    wave_lds_fence();

    // ---- Epilogue: outputs from window; broadcast coefficient reads; NT stores ----
    float* outB = out + ((size_t)b * S_ + s0) * D_ + d0;
    #pragma unroll
    for (int sl = 0; sl < CHUNK; ++sl) {
        const float4 g0 = *(const float4*)&gco[wave][sl][0];   // g[0..3]
        const float4 g1 = *(const float4*)&gco[wave][sl][4];   // g[4..7]
        const float  g8 = gco[wave][sl][8];

        float ax = g0.x * win[sl].x;
        float ay = g0.x * win[sl].y;
        float az = g0.x * win[sl].z;
        float aw = g0.x * win[sl].w;
        const float gs[8] = {g0.y, g0.z, g0.w, g1.x, g1.y, g1.z, g1.w, g8};
        #pragma unroll
        for (int jr = 1; jr <= MAXD; ++jr) {
            const float g = gs[jr - 1];
            ax += g * win[sl + jr].x;
            ay += g * win[sl + jr].y;
            az += g * win[sl + jr].z;
            aw += g * win[sl + jr].w;
        }
        fx4 acc4; acc4.x = ax; acc4.y = ay; acc4.z = az; acc4.w = aw;
        __builtin_nontemporal_store(acc4, (fx4*)(outB + (size_t)sl * D_));
    }
}

extern "C" void kernel_launch(void* const* d_in, const int* in_sizes, int n_in,
                              void* d_out, int out_size, void* d_ws, size_t ws_size,
                              hipStream_t stream) {
    const float* emb = (const float*)d_in[0];
    float* out = (float*)d_out;

    dim3 grid(NWG);      // 512 blocks, swizzled in-kernel
    dim3 block(256);
    traj_splat_kernel<<<grid, block, 0, stream>>>(emb, out);
}